// Round 6
// baseline (155.613 us; speedup 1.0000x reference)
//
#include <hip/hip_runtime.h>
#include <math.h>

#define B_  16
#define C_  512
#define A_  64
#define CV  448     // C - A (value / z_img dims)
#define G_  256
#define HW  256
#define SMX 256     // padded S (Smax)
#define BSP 4       // b-rows per block (4 blocks per group)

// ---------------- K1: spatial mean pool + per-group size ---------------------
// Blocks 0..255 additionally compute sgArr[g] = #valid s for group g.
__global__ __launch_bounds__(256) void meanpool_kernel(const float* __restrict__ Zimg,
                                                       float* __restrict__ z,
                                                       const int* __restrict__ pad_idx,
                                                       int* __restrict__ sgArr,
                                                       int Smax, int N) {
  const int bid = blockIdx.x, t = threadIdx.x;
  const int lane = t & 63, wave = t >> 6;
  __shared__ int r4[4];

  if (bid < G_) {                       // group size (prefix-contiguous validity)
    int v = pad_idx[(size_t)bid * Smax + t];
    bool ok = ((t == 0) || (v != 0)) && (v >= 0) && (v < N);
    int sgv = ok ? (t + 1) : 0;
    #pragma unroll
    for (int off = 32; off > 0; off >>= 1)
      sgv = max(sgv, __shfl_xor(sgv, off, 64));
    if (lane == 0) r4[wave] = sgv;
    __syncthreads();
    if (t == 0) sgArr[bid] = max(max(r4[0], r4[1]), max(r4[2], r4[3]));
  }

  int row = (bid << 2) + (t >> 6);      // b*C + c
  const float4* p = (const float4*)(Zimg + (size_t)row * HW);
  float4 v = p[lane];
  float s = (v.x + v.y) + (v.z + v.w);
  #pragma unroll
  for (int off = 32; off > 0; off >>= 1)
    s += __shfl_down(s, off, 64);
  if (lane == 0) z[row] = s * (1.0f / HW);
}

// ---------------- K2: bucket-rank groups by size (descending) ----------------
// 1 block, 256 thr. grank[r] = group with approx rank r (big -> small, 32-wide
// buckets). Pair sums grank[p]+grank[255-p] are near-constant -> mixed loads.
__global__ __launch_bounds__(256) void sched_kernel(const int* __restrict__ sgArr,
                                                    int* __restrict__ grank) {
  __shared__ int cnt[8], base[8];
  const int t = threadIdx.x;
  if (t < 8) cnt[t] = 0;
  __syncthreads();
  int sg = sgArr[t];
  int bk = min(7, max(0, sg - 32) >> 5);       // 32..256 -> 0..7
  atomicAdd(&cnt[bk], 1);
  __syncthreads();
  if (t == 0) {
    int o = 0;
    for (int b = 7; b >= 0; b--) { base[b] = o; o += cnt[b]; }
  }
  __syncthreads();
  int r = atomicAdd(&base[bk], 1);
  grank[r] = t;
}

// ---------------- K3: fused scores + softmax + PV + M_img --------------------
// grid = 1024 (4 blocks/group, b-quarters), 512 thr, launch_bounds(512,8).
// Round-5 analysis: VALU work ~10.7us of 51us; rest = exposed latency at only
// 16 waves/CU (grid-capped 50% occupancy). Fix: BSP 8->4 halves LDS (23 KB)
// and registers -> 4 blocks/CU x 8 waves = 32 waves/CU (100% nominal).
// Mapping: p=bid&255, q=bid>>8; g = q<2 ? grank[p] : grank[255-p]; bq=q.
//  - group ranked r: bids {r, r+256, (255-r)+512, (255-r)+768} -> 2 XCD pairs
//    (r%8, (7-r)%8), value rows deduped pairwise in L2.
//  - slot p mixes quarters of a big group (q<2) and a small group (q>=2).
// Phase A: thread (s=t>>1, kh=t&1): 32-dim half-dot for 4 b, UNCONDITIONAL
//          loads (guarded version spilled in r4); shfl_xor(1) combine; block
//          softmax; attn -> LDS (0 past sg).
// Phase B: wave=(ch,sh); lane=(cl,h). 8 gathered float4/thread in flight;
//          attn reads broadcast; cross-wave combine via redS + shfl_xor(32).
__global__ __launch_bounds__(512, 8) void fused_kernel(
    const float* __restrict__ Zsnd,
    const int*   __restrict__ pad_idx,
    const float* __restrict__ z,
    const int*   __restrict__ grank,
    float*       __restrict__ Mimg,
    float*       __restrict__ Msnd,
    int Smax, int N)
{
  const int bid  = blockIdx.x;
  const int p_   = bid & 255;
  const int q_   = bid >> 8;                // 0..3 = b-quarter
  const int g    = (q_ < 2) ? grank[p_] : grank[255 - p_];
  const int b0   = q_ * BSP;
  const int t    = threadIdx.x;
  const int lane = t & 63;
  const int wave = t >> 6;

  __shared__ float qs[BSP * A_];            // 1 KB
  __shared__ float attnT[SMX * BSP];        // 4 KB  [s][b-local]
  __shared__ int   idxs[SMX];               // 1 KB
  __shared__ float red[8 * BSP];
  __shared__ float red2[8 * BSP];
  __shared__ int   redi[8];
  __shared__ float redS[4 * BSP * 64 * 4];  // 16 KB [ch][b][lane] float4

  // ---- stage: validity/idx, queries, M_img broadcast ----
  int sgv = 0;
  if (t < SMX) {
    int v = pad_idx[(size_t)g * Smax + t];
    bool ok = ((t == 0) || (v != 0)) && (v >= 0) && (v < N);
    idxs[t] = ok ? v : 0;
    sgv = ok ? (t + 1) : 0;
  }
  #pragma unroll
  for (int off = 32; off > 0; off >>= 1)
    sgv = max(sgv, __shfl_xor(sgv, off, 64));
  if (lane == 0) redi[wave] = sgv;

  if (t < BSP * 16) {                       // 4 b x 16 a4 = 64 float4s
    int b = t >> 4, a4 = t & 15;
    *(float4*)(qs + b * A_ + a4 * 4) =
        *(const float4*)(z + (b0 + b) * C_ + CV + a4 * 4);
  }

  if (t < BSP * 112) {                      // Mimg[g, b0+b, :] = z[b0+b, :CV]
    int b = t / 112, c4 = t % 112;
    *(float4*)(Mimg + (size_t)g * (B_ * CV) + (b0 + b) * CV + c4 * 4) =
        *(const float4*)(z + (b0 + b) * C_ + c4 * 4);
  }

  __syncthreads();
  const int sg = max(max(max(redi[0], redi[1]), max(redi[2], redi[3])),
                     max(max(redi[4], redi[5]), max(redi[6], redi[7])));

  // ---- Phase A: scores (split-K over kh) ----
  const int s_ = t >> 1;
  const int kh = t & 1;
  const bool valid = (s_ < sg);             // prefix-contiguous validity
  const float* krow = Zsnd + (size_t)idxs[s_] * C_ + CV + kh * 32;

  float sc[BSP];
  #pragma unroll
  for (int b = 0; b < BSP; b++) sc[b] = 0.0f;

  #pragma unroll
  for (int c = 0; c < 2; c++) {
    float4 k0 = *(const float4*)(krow + c * 16 + 0);
    float4 k1 = *(const float4*)(krow + c * 16 + 4);
    float4 k2 = *(const float4*)(krow + c * 16 + 8);
    float4 k3 = *(const float4*)(krow + c * 16 + 12);
    #pragma unroll
    for (int b = 0; b < BSP; b++) {
      const float* qb = qs + b * A_ + kh * 32 + c * 16;
      float4 q0 = *(const float4*)(qb + 0);
      float4 q1 = *(const float4*)(qb + 4);
      float4 q2 = *(const float4*)(qb + 8);
      float4 q3 = *(const float4*)(qb + 12);
      sc[b] += q0.x * k0.x + q0.y * k0.y + q0.z * k0.z + q0.w * k0.w
             + q1.x * k1.x + q1.y * k1.y + q1.z * k1.z + q1.w * k1.w
             + q2.x * k2.x + q2.y * k2.y + q2.z * k2.z + q2.w * k2.w
             + q3.x * k3.x + q3.y * k3.y + q3.z * k3.z + q3.w * k3.w;
    }
    __builtin_amdgcn_sched_barrier(0);      // cap live values (anti-spill)
  }
  #pragma unroll
  for (int b = 0; b < BSP; b++)
    sc[b] += __shfl_xor(sc[b], 1, 64);      // combine kh halves: full dot

  // ---- softmax over s (butterfly within wave, LDS across 8 waves) ----
  #pragma unroll
  for (int b = 0; b < BSP; b++) {
    float v = valid ? sc[b] : -INFINITY;
    #pragma unroll
    for (int off = 32; off > 0; off >>= 1)
      v = fmaxf(v, __shfl_xor(v, off, 64));
    if (lane == 0) red[wave * BSP + b] = v;
  }
  __syncthreads();

  float ex[BSP];
  #pragma unroll
  for (int b = 0; b < BSP; b++) {
    float gm = red[0 * BSP + b];
    #pragma unroll
    for (int w2 = 1; w2 < 8; w2++) gm = fmaxf(gm, red[w2 * BSP + b]);
    float e = valid ? __expf(sc[b] - gm) : 0.0f;
    ex[b] = e;
    float es = (kh == 0) ? e : 0.0f;        // count each s once
    #pragma unroll
    for (int off = 32; off > 0; off >>= 1)
      es += __shfl_xor(es, off, 64);
    if (lane == 0) red2[wave * BSP + b] = es;
  }
  __syncthreads();

  if (kh == 0) {
    float iv[BSP];
    #pragma unroll
    for (int b = 0; b < BSP; b++) {
      float gs = red2[0 * BSP + b];
      #pragma unroll
      for (int w2 = 1; w2 < 8; w2++) gs += red2[w2 * BSP + b];
      iv[b] = ex[b] / gs;
    }
    *(float4*)(attnT + s_ * BSP) = make_float4(iv[0], iv[1], iv[2], iv[3]);
  }
  __syncthreads();

  // ---- Phase B: weighted value sum (32 s per iter, 8 gathers in flight) ----
  const int ch = wave >> 1;                 // column chunk (0..3)
  const int sh = wave & 1;                  // s parity
  const int cl = lane & 31;                 // float4 column slot
  const int h  = lane >> 5;                 // s sub-parity
  const int c0 = ch * 128;
  const int sg32 = (sg + 31) & ~31;         // attnT==0 past sg -> pad is exact

  const float* vbase = Zsnd + c0 + cl * 4;  // + idx*C_ ; col <= 508 in-row
  float4 acc[BSP];
  #pragma unroll
  for (int b = 0; b < BSP; b++) acc[b] = make_float4(0.f, 0.f, 0.f, 0.f);

  for (int s0 = 0; s0 < sg32; s0 += 32) {
    float4 v[8];
    #pragma unroll
    for (int j = 0; j < 8; j++) {
      int so = s0 + 4 * j + 2 * sh + h;
      v[j] = *(const float4*)(vbase + (size_t)idxs[so] * C_);
    }
    #pragma unroll
    for (int j = 0; j < 8; j++) {
      int so = s0 + 4 * j + 2 * sh + h;
      float4 w0 = *(const float4*)(attnT + so * BSP);       // b 0..3 (broadcast)
      float4 vv = v[j];
      acc[0].x += w0.x * vv.x; acc[0].y += w0.x * vv.y; acc[0].z += w0.x * vv.z; acc[0].w += w0.x * vv.w;
      acc[1].x += w0.y * vv.x; acc[1].y += w0.y * vv.y; acc[1].z += w0.y * vv.z; acc[1].w += w0.y * vv.w;
      acc[2].x += w0.z * vv.x; acc[2].y += w0.z * vv.y; acc[2].z += w0.z * vv.z; acc[2].w += w0.z * vv.w;
      acc[3].x += w0.w * vv.x; acc[3].y += w0.w * vv.y; acc[3].z += w0.w * vv.z; acc[3].w += w0.w * vv.w;
    }
  }

  // ---- cross-wave combine: sh==1 partials -> LDS, sh==0 adds + h-shfl ----
  if (sh == 1) {
    #pragma unroll
    for (int b = 0; b < BSP; b++)
      *(float4*)(redS + (((size_t)ch * BSP + b) * 64 + lane) * 4) = acc[b];
  }
  __syncthreads();
  if (sh == 0) {
    #pragma unroll
    for (int b = 0; b < BSP; b++) {
      float4 o = *(const float4*)(redS + (((size_t)ch * BSP + b) * 64 + lane) * 4);
      acc[b].x += o.x; acc[b].y += o.y; acc[b].z += o.z; acc[b].w += o.w;
      acc[b].x += __shfl_xor(acc[b].x, 32, 64);
      acc[b].y += __shfl_xor(acc[b].y, 32, 64);
      acc[b].z += __shfl_xor(acc[b].z, 32, 64);
      acc[b].w += __shfl_xor(acc[b].w, 32, 64);
    }
    if (h == 0 && c0 + cl * 4 < CV) {
      float* obase = Msnd + (size_t)g * (B_ * CV) + (size_t)b0 * CV + c0 + cl * 4;
      #pragma unroll
      for (int b = 0; b < BSP; b++)
        *(float4*)(obase + b * CV) = acc[b];
    }
  }
}

extern "C" void kernel_launch(void* const* d_in, const int* in_sizes, int n_in,
                              void* d_out, int out_size, void* d_ws, size_t ws_size,
                              hipStream_t stream) {
  const float* Zimg   = (const float*)d_in[0];
  const float* Zsnd   = (const float*)d_in[1];
  const int*   padidx = (const int*)d_in[2];
  // d_in[3] = pad_mask (unused; validity derived from pad_idx)
  // d_in[4] = attn_dims (constant 64)

  const int N    = in_sizes[1] / C_;     // rows in Z_snd
  const int Smax = in_sizes[2] / G_;     // padded sequence length (== 256)

  float* z     = (float*)d_ws;                            // B*C fp32
  int*   sgArr = (int*)(z + B_ * C_);                     // 256 ints
  int*   grank = sgArr + G_;                              // 256 ints
  float* Mimg = (float*)d_out;
  float* Msnd = Mimg + (size_t)G_ * B_ * CV;

  meanpool_kernel<<<(B_ * C_) / 4, 256, 0, stream>>>(Zimg, z, padidx, sgArr, Smax, N);
  sched_kernel<<<1, 256, 0, stream>>>(sgArr, grank);
  fused_kernel<<<G_ * 4, 512, 0, stream>>>(Zsnd, padidx, z, grank, Mimg, Msnd, Smax, N);
}